// Round 19
// baseline (166.782 us; speedup 1.0000x reference)
//
#include <hip/hip_runtime.h>
#include <hip/hip_bf16.h>
#include <stdint.h>

#define NTOK 4096
#define DM   1024
#define NH   16
#define DH   64
#define SCL  0.1803368801111129f   /* 0.125 * log2(e) */
#define LOG2E 1.4426950408889634f

typedef __attribute__((ext_vector_type(8)))  short bf16x8;
typedef __attribute__((ext_vector_type(4)))  float f32x4;
typedef __attribute__((ext_vector_type(16))) float f32x16;
typedef __attribute__((ext_vector_type(4)))  unsigned short us4;

__device__ inline unsigned short f2bf(float f) {
  union { float f; unsigned int u; } a;
  a.f = f;
  unsigned int u = a.u;
  u += 0x7fffu + ((u >> 16) & 1u);
  return (unsigned short)(u >> 16);
}

__device__ inline float bf2f(unsigned short v) {
  union { unsigned int u; float f; } a;
  a.u = ((unsigned int)v) << 16;
  return a.f;
}

__device__ inline unsigned int cvtpk_bf16(float lo, float hi) {
  unsigned int r;
  asm("v_cvt_pk_bf16_f32 %0, %1, %2" : "=v"(r) : "v"(lo), "v"(hi));
  return r;
}

__device__ inline void gload_lds16(const void* gsrc, void* ldst) {
  __builtin_amdgcn_global_load_lds(
      (const __attribute__((address_space(1))) void*)(uintptr_t)gsrc,
      (__attribute__((address_space(3))) void*)(unsigned int)(uintptr_t)ldst,
      16, 0, 0);
}

// ------- fused f32->bf16 conversions + hperm prep (single launch) ----------
__global__ void cvt_fused(const float* __restrict__ x,
                          const float* __restrict__ Wq,
                          const float* __restrict__ Wk,
                          const float* __restrict__ Wv,
                          const float* __restrict__ Wo,
                          const float* __restrict__ h,
                          unsigned short* __restrict__ xb,
                          unsigned short* __restrict__ wqkvb,
                          unsigned short* __restrict__ wob,
                          float* __restrict__ hperm) {
  const int b = blockIdx.x;
  if (b >= 8192) {                      // hperm: 16 blocks x 256 = 4096
    int i = (b - 8192) * 256 + threadIdx.x;
    int r  = i & 15;
    int hh = (i >> 4) & 1;
    int t  = i >> 5;
    int key = t * 32 + (r & 3) + 8 * (r >> 2) + 4 * hh;
    hperm[i] = -LOG2E * h[key];         // GAMMA = 1
    return;
  }
  int i = b * 256 + threadIdx.x;        // float4 index over 2M total
  const float* src; unsigned short* dst; int off;
  if (i < 1048576)      { src = x;  dst = xb;                 off = i; }
  else if (i < 1310720) { src = Wq; dst = wqkvb;              off = i - 1048576; }
  else if (i < 1572864) { src = Wk; dst = wqkvb + DM * DM;    off = i - 1310720; }
  else if (i < 1835008) { src = Wv; dst = wqkvb + 2 * DM * DM; off = i - 1572864; }
  else                  { src = Wo; dst = wob;                off = i - 1835008; }
  float4 v = ((const float4*)src)[off];
  us4 o;
  o[0] = f2bf(v.x); o[1] = f2bf(v.y); o[2] = f2bf(v.z); o[3] = f2bf(v.w);
  ((us4*)dst)[off] = o;
}

// ---------------- fused QKV GEMM: prefetch dbuf + LDS-repack epilogue ------
// Main loop: stage(t+1) before compute(t), one barrier/iter (T3 2-phase).
// Epilogue (Q/K regions): bias-applied bf16 results repacked through a
// pad-136 LDS tile -> coalesced 16B global stores (was 64 scalar 2B stores).
__global__ __launch_bounds__(256)
void gemm_qkv(const unsigned short* __restrict__ A,
              const unsigned short* __restrict__ B,
              const float* __restrict__ bq, const float* __restrict__ bk,
              const float* __restrict__ bv,
              unsigned short* __restrict__ Qb, unsigned short* __restrict__ Kb,
              unsigned short* __restrict__ Vt)
{
  const int bid = blockIdx.x;                        // 0..767
  const int wg  = (bid & 7) * 96 + (bid >> 3);       // bijective (768 = 8*96)
  const int bn  = (wg % 24) * 128;
  const int bm  = (wg / 24) * 128;
  const int tid  = threadIdx.x;
  const int wid  = tid >> 6;
  const int lane = tid & 63;
  const int wr = wid >> 1;
  const int wc = wid & 1;

  __shared__ __align__(16) char smem[32768];
  unsigned short (*As)[128 * 32] = (unsigned short(*)[128 * 32])smem;
  unsigned short (*Bs)[128 * 32] = (unsigned short(*)[128 * 32])(smem + 16384);

  f32x4 acc[4][4];
#pragma unroll
  for (int i = 0; i < 4; i++)
#pragma unroll
    for (int j = 0; j < 4; j++) acc[i][j] = f32x4{0.f, 0.f, 0.f, 0.f};

  const int fr = lane & 15;
  const int fk = (lane >> 4) * 8;
  const int srow = lane >> 2;
  const int scol = (lane & 3) * 8;
  const int ch0 = wid * 2, ch1 = wid * 2 + 1;
  const unsigned short* ag0 = A + (size_t)(bm + ch0 * 16 + srow) * DM + scol;
  const unsigned short* ag1 = A + (size_t)(bm + ch1 * 16 + srow) * DM + scol;
  const unsigned short* bg0 = B + (size_t)(bn + ch0 * 16 + srow) * DM + scol;
  const unsigned short* bg1 = B + (size_t)(bn + ch1 * 16 + srow) * DM + scol;

  // prologue: stage k-tile 0 into buf 0
  gload_lds16(ag0, &As[0][ch0 * 512]);
  gload_lds16(ag1, &As[0][ch1 * 512]);
  gload_lds16(bg0, &Bs[0][ch0 * 512]);
  gload_lds16(bg1, &Bs[0][ch1 * 512]);
  __syncthreads();

  int cur = 0;
  const int NK = DM / 32;                            // 32 k-tiles
  for (int t = 0; t < NK; ++t) {
    if (t + 1 < NK) {                                // prefetch next k-tile
      const int k1 = (t + 1) * 32;
      gload_lds16(ag0 + k1, &As[cur ^ 1][ch0 * 512]);
      gload_lds16(ag1 + k1, &As[cur ^ 1][ch1 * 512]);
      gload_lds16(bg0 + k1, &Bs[cur ^ 1][ch0 * 512]);
      gload_lds16(bg1 + k1, &Bs[cur ^ 1][ch1 * 512]);
    }
    bf16x8 af[4], bfr[4];
#pragma unroll
    for (int i = 0; i < 4; i++)
      af[i] = *(const bf16x8*)&As[cur][(wr * 64 + i * 16 + fr) * 32 + fk];
#pragma unroll
    for (int j = 0; j < 4; j++)
      bfr[j] = *(const bf16x8*)&Bs[cur][(wc * 64 + j * 16 + fr) * 32 + fk];
#pragma unroll
    for (int i = 0; i < 4; i++)
#pragma unroll
      for (int j = 0; j < 4; j++)
        acc[i][j] = __builtin_amdgcn_mfma_f32_16x16x32_bf16(af[i], bfr[j],
                                                            acc[i][j], 0, 0, 0);
    __syncthreads();                                 // next tile landed; reads done
    cur ^= 1;
  }

  const int fq = lane >> 4;
  const int region = bn >> 10;                       // 0=Q 1=K 2=V
  const float* bias = (region == 0) ? bq : (region == 1) ? bk : bv;
  const int cl0 = bn & 1023;

  if (region < 2) {
    // LDS-repack epilogue: pad-136 bf16 rows (272B: 16B-aligned; fq-groups
    // land 16 banks apart -> only free 2-way aliasing).
    const float qscale = (region == 0) ? SCL : 1.0f;
    unsigned short* rep = (unsigned short*)smem;     // 64 x 136 = 17408 B
    unsigned short* outp = (region == 0) ? Qb : Kb;
#pragma unroll
    for (int p = 0; p < 2; ++p) {
      __syncthreads();                               // previous smem use done
      if (wr == p) {
#pragma unroll
        for (int j = 0; j < 4; j++) {
          const int col = wc * 64 + j * 16 + fr;
          const float bvx = bias[cl0 + col];
#pragma unroll
          for (int i = 0; i < 4; i++) {
            const int rl = i * 16 + fq * 4;
#pragma unroll
            for (int r = 0; r < 4; r++)
              rep[(rl + r) * 136 + col] = f2bf((acc[i][j][r] + bvx) * qscale);
          }
        }
      }
      __syncthreads();
      // coalesced store: 64 rows x 16 chunks of 16B (4 per thread)
#pragma unroll
      for (int c = 0; c < 4; ++c) {
        const int unit = c * 256 + tid;
        const int row = unit >> 4;
        const int ch  = unit & 15;
        const bf16x8 v = *(const bf16x8*)&rep[row * 136 + ch * 8];
        *(bf16x8*)&outp[(size_t)(bm + p * 64 + row) * DM + cl0 + ch * 8] = v;
      }
    }
  } else {
    // V region: proven transposed us4 store (builds V^T)
#pragma unroll
    for (int j = 0; j < 4; j++) {
      const int col = bn + wc * 64 + j * 16 + fr;
      const int cl  = col & 1023;
      const float bvx = bias[cl];
#pragma unroll
      for (int i = 0; i < 4; i++) {
        const int row0 = bm + wr * 64 + i * 16 + fq * 4;
        us4 pk;
#pragma unroll
        for (int r = 0; r < 4; r++) pk[r] = f2bf(acc[i][j][r] + bvx);
        *(us4*)&Vt[(size_t)cl * NTOK + row0] = pk;
      }
    }
  }
}

// ------- final GEMM: prefetch double-buffer, 128x64 tiles, bf16 resid ------
__global__ __launch_bounds__(256)
void gemm_out(const unsigned short* __restrict__ A,
              const unsigned short* __restrict__ B,
              const float* __restrict__ bias,
              const unsigned short* __restrict__ residb,
              float* __restrict__ Cf)
{
  const int bid = blockIdx.x;                        // 0..511
  const int wg  = (bid & 7) * 64 + (bid >> 3);       // bijective (512 = 8*64)
  const int bn  = (wg % 16) * 64;
  const int bm  = (wg / 16) * 128;
  const int tid  = threadIdx.x;
  const int wid  = tid >> 6;
  const int lane = tid & 63;

  __shared__ __align__(16) unsigned short As[2][128 * 32];
  __shared__ __align__(16) unsigned short Bs[2][64 * 32];

  f32x4 acc[2][4];
#pragma unroll
  for (int i = 0; i < 2; i++)
#pragma unroll
    for (int j = 0; j < 4; j++) acc[i][j] = f32x4{0.f, 0.f, 0.f, 0.f};

  const int fr = lane & 15;
  const int fk = (lane >> 4) * 8;
  const int srow = lane >> 2;
  const int scol = (lane & 3) * 8;

  // 12 chunks: 0-7 A, 8-11 B; each wave stages 3
  const unsigned short* gsrc[3];
  int ldst[3];
#pragma unroll
  for (int c = 0; c < 3; ++c) {
    const int chunk = wid * 3 + c;
    if (chunk < 8) {
      gsrc[c] = A + (size_t)(bm + chunk * 16 + srow) * DM + scol;
      ldst[c] = chunk * 512;                         // into As
    } else {
      gsrc[c] = B + (size_t)(bn + (chunk - 8) * 16 + srow) * DM + scol;
      ldst[c] = 0x40000 + (chunk - 8) * 512;         // flag: into Bs
    }
  }

  // prologue: stage k-tile 0 into buf 0
#pragma unroll
  for (int c = 0; c < 3; ++c) {
    if (ldst[c] < 0x40000) gload_lds16(gsrc[c], &As[0][ldst[c]]);
    else                   gload_lds16(gsrc[c], &Bs[0][ldst[c] - 0x40000]);
  }
  __syncthreads();

  int cur = 0;
  const int NK = DM / 32;
  for (int t = 0; t < NK; ++t) {
    if (t + 1 < NK) {
      const int k1 = (t + 1) * 32;
#pragma unroll
      for (int c = 0; c < 3; ++c) {
        if (ldst[c] < 0x40000) gload_lds16(gsrc[c] + k1, &As[cur ^ 1][ldst[c]]);
        else                   gload_lds16(gsrc[c] + k1, &Bs[cur ^ 1][ldst[c] - 0x40000]);
      }
    }
    bf16x8 af[2], bfr[4];
#pragma unroll
    for (int i = 0; i < 2; i++)
      af[i] = *(const bf16x8*)&As[cur][(wid * 32 + i * 16 + fr) * 32 + fk];
#pragma unroll
    for (int j = 0; j < 4; j++)
      bfr[j] = *(const bf16x8*)&Bs[cur][(j * 16 + fr) * 32 + fk];
#pragma unroll
    for (int i = 0; i < 2; i++)
#pragma unroll
      for (int j = 0; j < 4; j++)
        acc[i][j] = __builtin_amdgcn_mfma_f32_16x16x32_bf16(af[i], bfr[j],
                                                            acc[i][j], 0, 0, 0);
    __syncthreads();
    cur ^= 1;
  }

  const int fq = lane >> 4;
#pragma unroll
  for (int j = 0; j < 4; j++) {
    const int col = bn + j * 16 + fr;
    const float bvx = bias[col];
#pragma unroll
    for (int i = 0; i < 2; i++) {
      const int row0 = bm + wid * 32 + i * 16 + fq * 4;
#pragma unroll
      for (int r = 0; r < 4; r++) {
        const size_t idx = (size_t)(row0 + r) * DM + col;
        Cf[idx] = acc[i][j][r] + bvx + bf2f(residb[idx]);
      }
    }
  }
}

// ---------------- attention (round-8 exact: empirical floor ~90us) ---------
#define MFMA32(a, b, c) __builtin_amdgcn_mfma_f32_32x32x16_bf16(a, b, c, 0, 0, 0)

__global__ __launch_bounds__(512)
void attn_kernel(const unsigned short* __restrict__ Q,
                 const unsigned short* __restrict__ K,
                 const unsigned short* __restrict__ Vt,
                 const float* __restrict__ hperm,
                 unsigned short* __restrict__ O)
{
  const int wgid = (blockIdx.x & 7) * 64 + (blockIdx.x >> 3);
  const int head = wgid >> 5;
  const int qblk = wgid & 31;
  const int tid  = threadIdx.x;
  const int wid  = tid >> 6;
  const int grp  = wid >> 2;
  const int w4   = wid & 3;
  const int lane = tid & 63;
  const int c31  = lane & 31;
  const int hi   = lane >> 5;
  const int qwb  = qblk * 128 + w4 * 32;
  const int k0g  = grp * 2048;

  __shared__ __align__(16) char lds_raw[32768];
  char* kbase = lds_raw + grp * 16384;
  char* vbase = kbase + 8192;

  const int srow = w4 * 4 + (lane >> 4);
  const int ssl  = lane & 15;
  const int sq   = ssl ^ srow;
  const int kkey = srow + 16 * (sq >> 3);
  const unsigned short* kg =
      K + (size_t)(k0g + kkey) * DM + head * DH + (sq & 7) * 8;
  const int vd = (sq >> 2) * 16 + srow;
  const unsigned short* vg =
      Vt + (size_t)(head * DH + vd) * NTOK + k0g + (sq & 3) * 8;

  const int fr15 = c31 & 15;
  const int fkh  = c31 >> 4;
  int koffB[4], voffB[2][2];
#pragma unroll
  for (int f = 0; f < 4; f++)
    koffB[f] = fr15 * 256 + (((fkh * 8 + f * 2 + hi) ^ fr15) << 4);
#pragma unroll
  for (int db = 0; db < 2; db++)
#pragma unroll
    for (int ko = 0; ko < 2; ko++)
      voffB[db][ko] =
          fr15 * 256 + ((((db * 2 + fkh) * 4 + ko * 2 + hi) ^ fr15) << 4);

  const unsigned short* qp = Q + (size_t)(qwb + c31) * DM + head * DH + hi * 8;
  const bf16x8 qf0 = *(const bf16x8*)(qp);
  const bf16x8 qf1 = *(const bf16x8*)(qp + 16);
  const bf16x8 qf2 = *(const bf16x8*)(qp + 32);
  const bf16x8 qf3 = *(const bf16x8*)(qp + 48);

  f32x16 o0, o1;
#pragma unroll
  for (int i = 0; i < 16; i++) { o0[i] = 0.f; o1[i] = 0.f; }
  float l = 0.f;

  gload_lds16(kg, kbase + w4 * 1024);
  gload_lds16(vg, vbase + w4 * 1024);
  __syncthreads();

  int cur = 0;
  const int NT = 2048 / 32;
  for (int t = 0; t < NT; ++t) {
    if (t + 1 < NT) {
      gload_lds16(kg + (size_t)(t + 1) * 32 * DM,
                  kbase + (cur ^ 1) * 4096 + w4 * 1024);
      gload_lds16(vg + (t + 1) * 32,
                  vbase + (cur ^ 1) * 4096 + w4 * 1024);
    }

    const float* hp = hperm + k0g + t * 32 + hi * 16;
    const float4 b0 = *(const float4*)(hp + 0);
    const float4 b1 = *(const float4*)(hp + 4);
    const float4 b2 = *(const float4*)(hp + 8);
    const float4 b3 = *(const float4*)(hp + 12);

    const char* Kb = kbase + cur * 4096;
    const char* Vb = vbase + cur * 4096;
    const bf16x8 kf0 = *(const bf16x8*)(Kb + koffB[0]);
    const bf16x8 kf1 = *(const bf16x8*)(Kb + koffB[1]);
    const bf16x8 kf2 = *(const bf16x8*)(Kb + koffB[2]);
    const bf16x8 kf3 = *(const bf16x8*)(Kb + koffB[3]);

    f32x16 s;
    s[0]  = b0.x; s[1]  = b0.y; s[2]  = b0.z; s[3]  = b0.w;
    s[4]  = b1.x; s[5]  = b1.y; s[6]  = b1.z; s[7]  = b1.w;
    s[8]  = b2.x; s[9]  = b2.y; s[10] = b2.z; s[11] = b2.w;
    s[12] = b3.x; s[13] = b3.y; s[14] = b3.z; s[15] = b3.w;

    s = MFMA32(kf0, qf0, s);
    s = MFMA32(kf1, qf1, s);
    s = MFMA32(kf2, qf2, s);
    s = MFMA32(kf3, qf3, s);

    const bf16x8 v00 = *(const bf16x8*)(Vb + voffB[0][0]);
    const bf16x8 v01 = *(const bf16x8*)(Vb + voffB[0][1]);
    const bf16x8 v10 = *(const bf16x8*)(Vb + voffB[1][0]);
    const bf16x8 v11 = *(const bf16x8*)(Vb + voffB[1][1]);

    float ps[16];
#pragma unroll
    for (int r = 0; r < 16; r++) ps[r] = __builtin_amdgcn_exp2f(s[r]);
    l += (((ps[0] + ps[1]) + (ps[2] + ps[3])) +
          ((ps[4] + ps[5]) + (ps[6] + ps[7]))) +
         (((ps[8] + ps[9]) + (ps[10] + ps[11])) +
          ((ps[12] + ps[13]) + (ps[14] + ps[15])));

    unsigned int X1 = cvtpk_bf16(ps[0],  ps[1]);
    unsigned int X2 = cvtpk_bf16(ps[2],  ps[3]);
    unsigned int Y1 = cvtpk_bf16(ps[4],  ps[5]);
    unsigned int Y2 = cvtpk_bf16(ps[6],  ps[7]);
    asm("v_permlane32_swap_b32 %0, %1" : "+v"(X1), "+v"(Y1));
    asm("v_permlane32_swap_b32 %0, %1" : "+v"(X2), "+v"(Y2));
    unsigned int X3 = cvtpk_bf16(ps[8],  ps[9]);
    unsigned int X4 = cvtpk_bf16(ps[10], ps[11]);
    unsigned int Y3 = cvtpk_bf16(ps[12], ps[13]);
    unsigned int Y4 = cvtpk_bf16(ps[14], ps[15]);
    asm("v_permlane32_swap_b32 %0, %1" : "+v"(X3), "+v"(Y3));
    asm("v_permlane32_swap_b32 %0, %1" : "+v"(X4), "+v"(Y4));

    union { unsigned int u[4]; bf16x8 v; } P0, P1;
    P0.u[0] = X1; P0.u[1] = X2; P0.u[2] = Y1; P0.u[3] = Y2;
    P1.u[0] = X3; P1.u[1] = X4; P1.u[2] = Y3; P1.u[3] = Y4;

    o0 = MFMA32(v00, P0.v, o0);
    o0 = MFMA32(v01, P1.v, o0);
    o1 = MFMA32(v10, P0.v, o1);
    o1 = MFMA32(v11, P1.v, o1);

    __syncthreads();
    cur ^= 1;
  }

  l += __shfl_xor(l, 32, 64);

  float* mo = (float*)lds_raw;
  float* mL = (float*)(lds_raw + 17408);
  float* row = &mo[(w4 * 64 + lane) * 17];
#pragma unroll
  for (int half = 0; half < 2; half++) {
    __syncthreads();
    if (grp == 1) {
      const f32x16& hA = half ? o1 : o0;
#pragma unroll
      for (int i = 0; i < 16; i++) row[i] = hA[i];
      if (half == 0 && hi == 0) mL[w4 * 32 + c31] = l;
    }
    __syncthreads();
    if (grp == 0) {
      f32x16& hA = half ? o1 : o0;
#pragma unroll
      for (int i = 0; i < 16; i++) hA[i] += row[i];
      if (half == 0) l += mL[w4 * 32 + c31];
    }
  }

  if (grp == 0) {
    const float inv = 1.0f / l;
    unsigned short* ob = O + (size_t)(qwb + c31) * DM + head * DH;
#pragma unroll
    for (int g = 0; g < 4; g++) {
      us4 pk;
      pk[0] = f2bf(o0[4 * g + 0] * inv); pk[1] = f2bf(o0[4 * g + 1] * inv);
      pk[2] = f2bf(o0[4 * g + 2] * inv); pk[3] = f2bf(o0[4 * g + 3] * inv);
      *(us4*)(ob + 8 * g + 4 * hi) = pk;
      pk[0] = f2bf(o1[4 * g + 0] * inv); pk[1] = f2bf(o1[4 * g + 1] * inv);
      pk[2] = f2bf(o1[4 * g + 2] * inv); pk[3] = f2bf(o1[4 * g + 3] * inv);
      *(us4*)(ob + 32 + 8 * g + 4 * hi) = pk;
    }
  }
}

extern "C" void kernel_launch(void* const* d_in, const int* in_sizes, int n_in,
                              void* d_out, int out_size, void* d_ws, size_t ws_size,
                              hipStream_t stream) {
  const float* x  = (const float*)d_in[0];
  const float* h  = (const float*)d_in[1];
  const float* Wq = (const float*)d_in[2];
  const float* bq = (const float*)d_in[3];
  const float* Wk = (const float*)d_in[4];
  const float* bk = (const float*)d_in[5];
  const float* Wv = (const float*)d_in[6];
  const float* bv = (const float*)d_in[7];
  const float* Wo = (const float*)d_in[8];
  const float* bo = (const float*)d_in[9];
  float* out = (float*)d_out;

  char* ws = (char*)d_ws;
  const size_t MB = 1 << 20;
  unsigned short* xb    = (unsigned short*)(ws + 0 * MB);   // 8 MB
  unsigned short* wqkvb = (unsigned short*)(ws + 8 * MB);   // 6 MB
  unsigned short* wob   = (unsigned short*)(ws + 14 * MB);  // 2 MB
  unsigned short* Qb    = (unsigned short*)(ws + 16 * MB);  // 8 MB
  unsigned short* Kb    = (unsigned short*)(ws + 24 * MB);  // 8 MB
  unsigned short* Vtb   = (unsigned short*)(ws + 32 * MB);  // 8 MB
  unsigned short* AOb   = (unsigned short*)(ws + 40 * MB);  // 8 MB
  float*          hperm = (float*)(ws + 48 * MB);           // 16 KB

  cvt_fused<<<8208, 256, 0, stream>>>(x, Wq, Wk, Wv, Wo, h,
                                      xb, wqkvb, wob, hperm);

  gemm_qkv<<<768, 256, 0, stream>>>(xb, wqkvb, bq, bk, bv, Qb, Kb, Vtb);

  attn_kernel<<<dim3(512), 512, 0, stream>>>(Qb, Kb, Vtb, hperm, AOb);

  gemm_out<<<512, 256, 0, stream>>>(AOb, wob, bo, xb, out);
}

// Round 20
// 159.191 us; speedup vs baseline: 1.0477x; 1.0477x over previous
//
#include <hip/hip_runtime.h>
#include <hip/hip_bf16.h>
#include <stdint.h>

#define NTOK 4096
#define DM   1024
#define NH   16
#define DH   64
#define SCL  0.1803368801111129f   /* 0.125 * log2(e) */
#define LOG2E 1.4426950408889634f

typedef __attribute__((ext_vector_type(8)))  short bf16x8;
typedef __attribute__((ext_vector_type(4)))  float f32x4;
typedef __attribute__((ext_vector_type(16))) float f32x16;
typedef __attribute__((ext_vector_type(4)))  unsigned short us4;

__device__ inline unsigned short f2bf(float f) {
  union { float f; unsigned int u; } a;
  a.f = f;
  unsigned int u = a.u;
  u += 0x7fffu + ((u >> 16) & 1u);
  return (unsigned short)(u >> 16);
}

__device__ inline float bf2f(unsigned short v) {
  union { unsigned int u; float f; } a;
  a.u = ((unsigned int)v) << 16;
  return a.f;
}

__device__ inline unsigned int cvtpk_bf16(float lo, float hi) {
  unsigned int r;
  asm("v_cvt_pk_bf16_f32 %0, %1, %2" : "=v"(r) : "v"(lo), "v"(hi));
  return r;
}

__device__ inline void gload_lds16(const void* gsrc, void* ldst) {
  __builtin_amdgcn_global_load_lds(
      (const __attribute__((address_space(1))) void*)(uintptr_t)gsrc,
      (__attribute__((address_space(3))) void*)(unsigned int)(uintptr_t)ldst,
      16, 0, 0);
}

// ------- fused f32->bf16 conversions + hperm prep (single launch) ----------
__global__ void cvt_fused(const float* __restrict__ x,
                          const float* __restrict__ Wq,
                          const float* __restrict__ Wk,
                          const float* __restrict__ Wv,
                          const float* __restrict__ Wo,
                          const float* __restrict__ h,
                          unsigned short* __restrict__ xb,
                          unsigned short* __restrict__ wqkvb,
                          unsigned short* __restrict__ wob,
                          float* __restrict__ hperm) {
  const int b = blockIdx.x;
  if (b >= 8192) {                      // hperm: 16 blocks x 256 = 4096
    int i = (b - 8192) * 256 + threadIdx.x;
    int r  = i & 15;
    int hh = (i >> 4) & 1;
    int t  = i >> 5;
    int key = t * 32 + (r & 3) + 8 * (r >> 2) + 4 * hh;
    hperm[i] = -LOG2E * h[key];         // GAMMA = 1
    return;
  }
  int i = b * 256 + threadIdx.x;        // float4 index over 2M total
  const float* src; unsigned short* dst; int off;
  if (i < 1048576)      { src = x;  dst = xb;                 off = i; }
  else if (i < 1310720) { src = Wq; dst = wqkvb;              off = i - 1048576; }
  else if (i < 1572864) { src = Wk; dst = wqkvb + DM * DM;    off = i - 1310720; }
  else if (i < 1835008) { src = Wv; dst = wqkvb + 2 * DM * DM; off = i - 1572864; }
  else                  { src = Wo; dst = wob;                off = i - 1835008; }
  float4 v = ((const float4*)src)[off];
  us4 o;
  o[0] = f2bf(v.x); o[1] = f2bf(v.y); o[2] = f2bf(v.z); o[3] = f2bf(v.w);
  ((us4*)dst)[off] = o;
}

// ---------------- fused QKV GEMM: prefetch double-buffer (attn-style) ------
// stage(t+1) issued BEFORE compute(t); single barrier per iteration drains
// loads that had the whole compute phase to land.
__global__ __launch_bounds__(256)
void gemm_qkv(const unsigned short* __restrict__ A,
              const unsigned short* __restrict__ B,
              const float* __restrict__ bq, const float* __restrict__ bk,
              const float* __restrict__ bv,
              unsigned short* __restrict__ Qb, unsigned short* __restrict__ Kb,
              unsigned short* __restrict__ Vt)
{
  const int bid = blockIdx.x;                        // 0..767
  const int wg  = (bid & 7) * 96 + (bid >> 3);       // bijective (768 = 8*96)
  const int bn  = (wg % 24) * 128;
  const int bm  = (wg / 24) * 128;
  const int tid  = threadIdx.x;
  const int wid  = tid >> 6;
  const int lane = tid & 63;
  const int wr = wid >> 1;
  const int wc = wid & 1;

  __shared__ __align__(16) unsigned short As[2][128 * 32];
  __shared__ __align__(16) unsigned short Bs[2][128 * 32];

  f32x4 acc[4][4];
#pragma unroll
  for (int i = 0; i < 4; i++)
#pragma unroll
    for (int j = 0; j < 4; j++) acc[i][j] = f32x4{0.f, 0.f, 0.f, 0.f};

  const int fr = lane & 15;
  const int fk = (lane >> 4) * 8;
  const int srow = lane >> 2;
  const int scol = (lane & 3) * 8;
  const int ch0 = wid * 2, ch1 = wid * 2 + 1;
  const unsigned short* ag0 = A + (size_t)(bm + ch0 * 16 + srow) * DM + scol;
  const unsigned short* ag1 = A + (size_t)(bm + ch1 * 16 + srow) * DM + scol;
  const unsigned short* bg0 = B + (size_t)(bn + ch0 * 16 + srow) * DM + scol;
  const unsigned short* bg1 = B + (size_t)(bn + ch1 * 16 + srow) * DM + scol;

  // prologue: stage k-tile 0 into buf 0
  gload_lds16(ag0, &As[0][ch0 * 512]);
  gload_lds16(ag1, &As[0][ch1 * 512]);
  gload_lds16(bg0, &Bs[0][ch0 * 512]);
  gload_lds16(bg1, &Bs[0][ch1 * 512]);
  __syncthreads();

  int cur = 0;
  const int NK = DM / 32;                            // 32 k-tiles
  for (int t = 0; t < NK; ++t) {
    if (t + 1 < NK) {                                // prefetch next k-tile
      const int k1 = (t + 1) * 32;
      gload_lds16(ag0 + k1, &As[cur ^ 1][ch0 * 512]);
      gload_lds16(ag1 + k1, &As[cur ^ 1][ch1 * 512]);
      gload_lds16(bg0 + k1, &Bs[cur ^ 1][ch0 * 512]);
      gload_lds16(bg1 + k1, &Bs[cur ^ 1][ch1 * 512]);
    }
    bf16x8 af[4], bfr[4];
#pragma unroll
    for (int i = 0; i < 4; i++)
      af[i] = *(const bf16x8*)&As[cur][(wr * 64 + i * 16 + fr) * 32 + fk];
#pragma unroll
    for (int j = 0; j < 4; j++)
      bfr[j] = *(const bf16x8*)&Bs[cur][(wc * 64 + j * 16 + fr) * 32 + fk];
#pragma unroll
    for (int i = 0; i < 4; i++)
#pragma unroll
      for (int j = 0; j < 4; j++)
        acc[i][j] = __builtin_amdgcn_mfma_f32_16x16x32_bf16(af[i], bfr[j],
                                                            acc[i][j], 0, 0, 0);
    __syncthreads();                                 // next tile landed; reads done
    cur ^= 1;
  }

  const int fq = lane >> 4;
  const int region = bn >> 10;                       // 0=Q 1=K 2=V
  const float* bias = (region == 0) ? bq : (region == 1) ? bk : bv;
  const float qscale = (region == 0) ? SCL : 1.0f;
  unsigned short* outp = (region == 0) ? Qb : Kb;
#pragma unroll
  for (int j = 0; j < 4; j++) {
    const int col = bn + wc * 64 + j * 16 + fr;
    const int cl  = col & 1023;
    const float bvx = bias[cl];
#pragma unroll
    for (int i = 0; i < 4; i++) {
      const int row0 = bm + wr * 64 + i * 16 + fq * 4;
      if (region < 2) {
#pragma unroll
        for (int r = 0; r < 4; r++)
          outp[(size_t)(row0 + r) * DM + cl] = f2bf((acc[i][j][r] + bvx) * qscale);
      } else {
        us4 pk;
#pragma unroll
        for (int r = 0; r < 4; r++) pk[r] = f2bf(acc[i][j][r] + bvx);
        *(us4*)&Vt[(size_t)cl * NTOK + row0] = pk;
      }
    }
  }
}

// ------- final GEMM: prefetch double-buffer, 128x64 tiles, bf16 resid ------
__global__ __launch_bounds__(256)
void gemm_out(const unsigned short* __restrict__ A,
              const unsigned short* __restrict__ B,
              const float* __restrict__ bias,
              const unsigned short* __restrict__ residb,
              float* __restrict__ Cf)
{
  const int bid = blockIdx.x;                        // 0..511
  const int wg  = (bid & 7) * 64 + (bid >> 3);       // bijective (512 = 8*64)
  const int bn  = (wg % 16) * 64;
  const int bm  = (wg / 16) * 128;
  const int tid  = threadIdx.x;
  const int wid  = tid >> 6;
  const int lane = tid & 63;

  __shared__ __align__(16) unsigned short As[2][128 * 32];
  __shared__ __align__(16) unsigned short Bs[2][64 * 32];

  f32x4 acc[2][4];
#pragma unroll
  for (int i = 0; i < 2; i++)
#pragma unroll
    for (int j = 0; j < 4; j++) acc[i][j] = f32x4{0.f, 0.f, 0.f, 0.f};

  const int fr = lane & 15;
  const int fk = (lane >> 4) * 8;
  const int srow = lane >> 2;
  const int scol = (lane & 3) * 8;

  // 12 chunks: 0-7 A, 8-11 B; each wave stages 3
  const unsigned short* gsrc[3];
  int ldst[3];
#pragma unroll
  for (int c = 0; c < 3; ++c) {
    const int chunk = wid * 3 + c;
    if (chunk < 8) {
      gsrc[c] = A + (size_t)(bm + chunk * 16 + srow) * DM + scol;
      ldst[c] = chunk * 512;                         // into As
    } else {
      gsrc[c] = B + (size_t)(bn + (chunk - 8) * 16 + srow) * DM + scol;
      ldst[c] = 0x40000 + (chunk - 8) * 512;         // flag: into Bs
    }
  }

  // prologue: stage k-tile 0 into buf 0
#pragma unroll
  for (int c = 0; c < 3; ++c) {
    if (ldst[c] < 0x40000) gload_lds16(gsrc[c], &As[0][ldst[c]]);
    else                   gload_lds16(gsrc[c], &Bs[0][ldst[c] - 0x40000]);
  }
  __syncthreads();

  int cur = 0;
  const int NK = DM / 32;
  for (int t = 0; t < NK; ++t) {
    if (t + 1 < NK) {
      const int k1 = (t + 1) * 32;
#pragma unroll
      for (int c = 0; c < 3; ++c) {
        if (ldst[c] < 0x40000) gload_lds16(gsrc[c] + k1, &As[cur ^ 1][ldst[c]]);
        else                   gload_lds16(gsrc[c] + k1, &Bs[cur ^ 1][ldst[c] - 0x40000]);
      }
    }
    bf16x8 af[2], bfr[4];
#pragma unroll
    for (int i = 0; i < 2; i++)
      af[i] = *(const bf16x8*)&As[cur][(wid * 32 + i * 16 + fr) * 32 + fk];
#pragma unroll
    for (int j = 0; j < 4; j++)
      bfr[j] = *(const bf16x8*)&Bs[cur][(j * 16 + fr) * 32 + fk];
#pragma unroll
    for (int i = 0; i < 2; i++)
#pragma unroll
      for (int j = 0; j < 4; j++)
        acc[i][j] = __builtin_amdgcn_mfma_f32_16x16x32_bf16(af[i], bfr[j],
                                                            acc[i][j], 0, 0, 0);
    __syncthreads();
    cur ^= 1;
  }

  const int fq = lane >> 4;
#pragma unroll
  for (int j = 0; j < 4; j++) {
    const int col = bn + j * 16 + fr;
    const float bvx = bias[col];
#pragma unroll
    for (int i = 0; i < 2; i++) {
      const int row0 = bm + wid * 32 + i * 16 + fq * 4;
#pragma unroll
      for (int r = 0; r < 4; r++) {
        const size_t idx = (size_t)(row0 + r) * DM + col;
        Cf[idx] = acc[i][j][r] + bvx + bf2f(residb[idx]);
      }
    }
  }
}

// ---------------- attention (round-8 exact: empirical floor ~90us) ---------
#define MFMA32(a, b, c) __builtin_amdgcn_mfma_f32_32x32x16_bf16(a, b, c, 0, 0, 0)

__global__ __launch_bounds__(512)
void attn_kernel(const unsigned short* __restrict__ Q,
                 const unsigned short* __restrict__ K,
                 const unsigned short* __restrict__ Vt,
                 const float* __restrict__ hperm,
                 unsigned short* __restrict__ O)
{
  const int wgid = (blockIdx.x & 7) * 64 + (blockIdx.x >> 3);
  const int head = wgid >> 5;
  const int qblk = wgid & 31;
  const int tid  = threadIdx.x;
  const int wid  = tid >> 6;
  const int grp  = wid >> 2;
  const int w4   = wid & 3;
  const int lane = tid & 63;
  const int c31  = lane & 31;
  const int hi   = lane >> 5;
  const int qwb  = qblk * 128 + w4 * 32;
  const int k0g  = grp * 2048;

  __shared__ __align__(16) char lds_raw[32768];
  char* kbase = lds_raw + grp * 16384;
  char* vbase = kbase + 8192;

  const int srow = w4 * 4 + (lane >> 4);
  const int ssl  = lane & 15;
  const int sq   = ssl ^ srow;
  const int kkey = srow + 16 * (sq >> 3);
  const unsigned short* kg =
      K + (size_t)(k0g + kkey) * DM + head * DH + (sq & 7) * 8;
  const int vd = (sq >> 2) * 16 + srow;
  const unsigned short* vg =
      Vt + (size_t)(head * DH + vd) * NTOK + k0g + (sq & 3) * 8;

  const int fr15 = c31 & 15;
  const int fkh  = c31 >> 4;
  int koffB[4], voffB[2][2];
#pragma unroll
  for (int f = 0; f < 4; f++)
    koffB[f] = fr15 * 256 + (((fkh * 8 + f * 2 + hi) ^ fr15) << 4);
#pragma unroll
  for (int db = 0; db < 2; db++)
#pragma unroll
    for (int ko = 0; ko < 2; ko++)
      voffB[db][ko] =
          fr15 * 256 + ((((db * 2 + fkh) * 4 + ko * 2 + hi) ^ fr15) << 4);

  const unsigned short* qp = Q + (size_t)(qwb + c31) * DM + head * DH + hi * 8;
  const bf16x8 qf0 = *(const bf16x8*)(qp);
  const bf16x8 qf1 = *(const bf16x8*)(qp + 16);
  const bf16x8 qf2 = *(const bf16x8*)(qp + 32);
  const bf16x8 qf3 = *(const bf16x8*)(qp + 48);

  f32x16 o0, o1;
#pragma unroll
  for (int i = 0; i < 16; i++) { o0[i] = 0.f; o1[i] = 0.f; }
  float l = 0.f;

  gload_lds16(kg, kbase + w4 * 1024);
  gload_lds16(vg, vbase + w4 * 1024);
  __syncthreads();

  int cur = 0;
  const int NT = 2048 / 32;
  for (int t = 0; t < NT; ++t) {
    if (t + 1 < NT) {
      gload_lds16(kg + (size_t)(t + 1) * 32 * DM,
                  kbase + (cur ^ 1) * 4096 + w4 * 1024);
      gload_lds16(vg + (t + 1) * 32,
                  vbase + (cur ^ 1) * 4096 + w4 * 1024);
    }

    const float* hp = hperm + k0g + t * 32 + hi * 16;
    const float4 b0 = *(const float4*)(hp + 0);
    const float4 b1 = *(const float4*)(hp + 4);
    const float4 b2 = *(const float4*)(hp + 8);
    const float4 b3 = *(const float4*)(hp + 12);

    const char* Kb = kbase + cur * 4096;
    const char* Vb = vbase + cur * 4096;
    const bf16x8 kf0 = *(const bf16x8*)(Kb + koffB[0]);
    const bf16x8 kf1 = *(const bf16x8*)(Kb + koffB[1]);
    const bf16x8 kf2 = *(const bf16x8*)(Kb + koffB[2]);
    const bf16x8 kf3 = *(const bf16x8*)(Kb + koffB[3]);

    f32x16 s;
    s[0]  = b0.x; s[1]  = b0.y; s[2]  = b0.z; s[3]  = b0.w;
    s[4]  = b1.x; s[5]  = b1.y; s[6]  = b1.z; s[7]  = b1.w;
    s[8]  = b2.x; s[9]  = b2.y; s[10] = b2.z; s[11] = b2.w;
    s[12] = b3.x; s[13] = b3.y; s[14] = b3.z; s[15] = b3.w;

    s = MFMA32(kf0, qf0, s);
    s = MFMA32(kf1, qf1, s);
    s = MFMA32(kf2, qf2, s);
    s = MFMA32(kf3, qf3, s);

    const bf16x8 v00 = *(const bf16x8*)(Vb + voffB[0][0]);
    const bf16x8 v01 = *(const bf16x8*)(Vb + voffB[0][1]);
    const bf16x8 v10 = *(const bf16x8*)(Vb + voffB[1][0]);
    const bf16x8 v11 = *(const bf16x8*)(Vb + voffB[1][1]);

    float ps[16];
#pragma unroll
    for (int r = 0; r < 16; r++) ps[r] = __builtin_amdgcn_exp2f(s[r]);
    l += (((ps[0] + ps[1]) + (ps[2] + ps[3])) +
          ((ps[4] + ps[5]) + (ps[6] + ps[7]))) +
         (((ps[8] + ps[9]) + (ps[10] + ps[11])) +
          ((ps[12] + ps[13]) + (ps[14] + ps[15])));

    unsigned int X1 = cvtpk_bf16(ps[0],  ps[1]);
    unsigned int X2 = cvtpk_bf16(ps[2],  ps[3]);
    unsigned int Y1 = cvtpk_bf16(ps[4],  ps[5]);
    unsigned int Y2 = cvtpk_bf16(ps[6],  ps[7]);
    asm("v_permlane32_swap_b32 %0, %1" : "+v"(X1), "+v"(Y1));
    asm("v_permlane32_swap_b32 %0, %1" : "+v"(X2), "+v"(Y2));
    unsigned int X3 = cvtpk_bf16(ps[8],  ps[9]);
    unsigned int X4 = cvtpk_bf16(ps[10], ps[11]);
    unsigned int Y3 = cvtpk_bf16(ps[12], ps[13]);
    unsigned int Y4 = cvtpk_bf16(ps[14], ps[15]);
    asm("v_permlane32_swap_b32 %0, %1" : "+v"(X3), "+v"(Y3));
    asm("v_permlane32_swap_b32 %0, %1" : "+v"(X4), "+v"(Y4));

    union { unsigned int u[4]; bf16x8 v; } P0, P1;
    P0.u[0] = X1; P0.u[1] = X2; P0.u[2] = Y1; P0.u[3] = Y2;
    P1.u[0] = X3; P1.u[1] = X4; P1.u[2] = Y3; P1.u[3] = Y4;

    o0 = MFMA32(v00, P0.v, o0);
    o0 = MFMA32(v01, P1.v, o0);
    o1 = MFMA32(v10, P0.v, o1);
    o1 = MFMA32(v11, P1.v, o1);

    __syncthreads();
    cur ^= 1;
  }

  l += __shfl_xor(l, 32, 64);

  float* mo = (float*)lds_raw;
  float* mL = (float*)(lds_raw + 17408);
  float* row = &mo[(w4 * 64 + lane) * 17];
#pragma unroll
  for (int half = 0; half < 2; half++) {
    __syncthreads();
    if (grp == 1) {
      const f32x16& hA = half ? o1 : o0;
#pragma unroll
      for (int i = 0; i < 16; i++) row[i] = hA[i];
      if (half == 0 && hi == 0) mL[w4 * 32 + c31] = l;
    }
    __syncthreads();
    if (grp == 0) {
      f32x16& hA = half ? o1 : o0;
#pragma unroll
      for (int i = 0; i < 16; i++) hA[i] += row[i];
      if (half == 0) l += mL[w4 * 32 + c31];
    }
  }

  if (grp == 0) {
    const float inv = 1.0f / l;
    unsigned short* ob = O + (size_t)(qwb + c31) * DM + head * DH;
#pragma unroll
    for (int g = 0; g < 4; g++) {
      us4 pk;
      pk[0] = f2bf(o0[4 * g + 0] * inv); pk[1] = f2bf(o0[4 * g + 1] * inv);
      pk[2] = f2bf(o0[4 * g + 2] * inv); pk[3] = f2bf(o0[4 * g + 3] * inv);
      *(us4*)(ob + 8 * g + 4 * hi) = pk;
      pk[0] = f2bf(o1[4 * g + 0] * inv); pk[1] = f2bf(o1[4 * g + 1] * inv);
      pk[2] = f2bf(o1[4 * g + 2] * inv); pk[3] = f2bf(o1[4 * g + 3] * inv);
      *(us4*)(ob + 32 + 8 * g + 4 * hi) = pk;
    }
  }
}

extern "C" void kernel_launch(void* const* d_in, const int* in_sizes, int n_in,
                              void* d_out, int out_size, void* d_ws, size_t ws_size,
                              hipStream_t stream) {
  const float* x  = (const float*)d_in[0];
  const float* h  = (const float*)d_in[1];
  const float* Wq = (const float*)d_in[2];
  const float* bq = (const float*)d_in[3];
  const float* Wk = (const float*)d_in[4];
  const float* bk = (const float*)d_in[5];
  const float* Wv = (const float*)d_in[6];
  const float* bv = (const float*)d_in[7];
  const float* Wo = (const float*)d_in[8];
  const float* bo = (const float*)d_in[9];
  float* out = (float*)d_out;

  char* ws = (char*)d_ws;
  const size_t MB = 1 << 20;
  unsigned short* xb    = (unsigned short*)(ws + 0 * MB);   // 8 MB
  unsigned short* wqkvb = (unsigned short*)(ws + 8 * MB);   // 6 MB
  unsigned short* wob   = (unsigned short*)(ws + 14 * MB);  // 2 MB
  unsigned short* Qb    = (unsigned short*)(ws + 16 * MB);  // 8 MB
  unsigned short* Kb    = (unsigned short*)(ws + 24 * MB);  // 8 MB
  unsigned short* Vtb   = (unsigned short*)(ws + 32 * MB);  // 8 MB
  unsigned short* AOb   = (unsigned short*)(ws + 40 * MB);  // 8 MB
  float*          hperm = (float*)(ws + 48 * MB);           // 16 KB

  cvt_fused<<<8208, 256, 0, stream>>>(x, Wq, Wk, Wv, Wo, h,
                                      xb, wqkvb, wob, hperm);

  gemm_qkv<<<768, 256, 0, stream>>>(xb, wqkvb, bq, bk, bv, Qb, Kb, Vtb);

  attn_kernel<<<dim3(512), 512, 0, stream>>>(Qb, Kb, Vtb, hperm, AOb);

  gemm_out<<<512, 256, 0, stream>>>(AOb, wob, bo, xb, out);
}